// Round 7
// baseline (273.994 us; speedup 1.0000x reference)
//
#include <hip/hip_runtime.h>
#include <stdint.h>
#include <math.h>

#define HH 256
#define WW 256
#define BATCH 16
#define HP 257            // pooled field is 257x257
#define SROW 264          // padded row stride (multiple of 4 -> vec4 rows)
#define SH 259            // padded rows (1 zero row top/bottom)
#define SBP (SH*SROW)     // per-batch padded s size
#define NBAND 64          // 4-row bands per batch (phases A and B)
#define NPART 64          // minmax partial sets per batch (one per A band)
#define NVIRT (BATCH*NBAND)  // 1024 virtual blocks per phase

// s layout: s[b][r][c], r=0..258, c=0..263. Core: pooled(h,w) at r=h+1, c=w+4.
// Pads: r=0, r=258 zero rows; cols 0..3 and 261..263 zero. Core cols 4..260.

struct SA { float xs[8][264]; float ps[7][264]; float redmn[4][8]; float redmx[4][8]; };
struct SB { float lh[4*64*32]; float band[7][264]; };
struct SC { float hh[4][64]; float w9l[3*9*56]; float wfl[144]; float wred[4][16];
            float gmn[8]; float gmx[8]; float gstat[8]; float glvl[8]; float sred[4]; };
union  SU { SA a; SB b; SC c; };   // max ~39.4 KB -> up to 4 blocks/CU

__device__ __forceinline__ float leaky(float v){ return v >= 0.f ? v : 0.01f*v; }

__device__ __forceinline__ void group_off(int k, int& dh, int& dw){
    dh = (k == 3) ? 0 : -1;
    dw = (k == 3) ? 1 : (k - 1);
}

// expand+leaky activation recompute (textually identical to the stored-hloc version)
__device__ __forceinline__ float expand_a(int ij, int o, float lvl0, float lvl1,
                                          const float* hh_g,
                                          const float* __restrict__ we,
                                          const float* __restrict__ be){
    int i = ij>>3, j = ij&7;
    float f0 = __fmul_rn((float)(i+1), lvl0);
    float f1 = __fmul_rn((float)(j+1), lvl1);
    float f2 = hh_g[ij];
    return leaky(f0*we[o*3+0] + f1*we[o*3+1] + f2*we[o*3+2] + be[o]);
}

// Device-scope semaphore barrier (validated in round 4 at 512 blocks).
// Safe iff all nblk blocks are co-resident (nblk computed from occupancy queries).
__device__ __forceinline__ void grid_barrier(unsigned* bar, int slot, int nblk){
    __syncthreads();
    if (threadIdx.x == 0){
        __threadfence();
        unsigned prev = __hip_atomic_fetch_add(&bar[slot*2], 1u, __ATOMIC_ACQ_REL,
                                               __HIP_MEMORY_SCOPE_AGENT);
        if (prev + 1u == (unsigned)nblk){
            __hip_atomic_store(&bar[slot*2+1], 1u, __ATOMIC_RELEASE, __HIP_MEMORY_SCOPE_AGENT);
        } else {
            while (__hip_atomic_load(&bar[slot*2+1], __ATOMIC_ACQUIRE,
                                     __HIP_MEMORY_SCOPE_AGENT) == 0u)
                __builtin_amdgcn_s_sleep(2);
        }
        __threadfence();
    }
    __syncthreads();
}

// ---- Phase A: 4-row band pool -> s + 8-diff minmax partials. va = b*NBAND + c ----
__device__ void phaseA(SA& A, int va, const float* __restrict__ x, float* __restrict__ s,
                       float* __restrict__ pmn, float* __restrict__ pmx, float* __restrict__ hist)
{
    int tid = threadIdx.x, wv = tid >> 6, lane = tid & 63;
    int c = va & (NBAND-1), b = va >> 6;
    int h0 = c*4;
    int nr = (c == NBAND-1) ? 5 : 4;

    if (va == 0){
        for (int t = tid; t < 4096; t += 256) hist[t] = 0.f;
    }
    float* sb = s + (size_t)b*SBP;
    for (int t = tid; t < nr*7; t += 256){
        int rr = t/7, k = t%7;
        int col = (k < 4) ? k : (257 + k);      // 0..3, 261..263
        sb[(size_t)(h0+1+rr)*SROW + col] = 0.f;
    }
    if (c == 0){        for (int t = tid; t < SROW; t += 256) sb[t] = 0.f; }
    if (c == NBAND-1){  for (int t = tid; t < SROW; t += 256) sb[(size_t)258*SROW + t] = 0.f; }

    // stage channel-summed X rows h0-2 .. h0+nr, cols -4..259 zero-padded, vec4
    const float* xb = x + (size_t)b*3*HH*WW;
    int nxr = nr + 3;
    for (int t = tid; t < nxr*66; t += 256){
        int i = t/66, q = t - i*66;
        int r = h0 - 2 + i;
        float4 v = make_float4(0.f, 0.f, 0.f, 0.f);
        if (q >= 1 && q <= 64 && (unsigned)r < 256u){
            const float* base = xb + (size_t)r*WW + (q-1)*4;
            float4 a = *(const float4*)(base);
            float4 d = *(const float4*)(base + HH*WW);
            float4 e = *(const float4*)(base + 2*HH*WW);
            v.x = a.x + d.x + e.x;
            v.y = a.y + d.y + e.y;
            v.z = a.z + d.z + e.z;
            v.w = a.w + d.w + e.w;
        }
        *(float4*)&A.xs[i][q*4] = v;
    }
    __syncthreads();

    // pooled rows j=0..nr+1 (pooled row h = h0-1+j); zero outside [0,257)
    int np = (nr+2)*257;
    for (int t = tid; t < np; t += 256){
        int j = t/257, w = t - j*257;
        int h = h0 - 1 + j;
        float v = 0.f;
        if ((unsigned)h < (unsigned)HP)
            v = 0.25f*(A.xs[j][w+3] + A.xs[j][w+4] + A.xs[j+1][w+3] + A.xs[j+1][w+4]);
        A.ps[j][w+4] = v;
    }
    for (int t = tid; t < (nr+2)*7; t += 256){
        int j = t/7, k = t%7;
        A.ps[j][(k < 4) ? k : (257 + k)] = 0.f;
    }
    __syncthreads();

    float mn[8], mx[8];
    #pragma unroll
    for (int q=0;q<8;q++){ mn[q]=INFINITY; mx[q]=-INFINITY; }
    int nd = nr*257;
    for (int t = tid; t < nd; t += 256){
        int lr = t/257, w = t - lr*257;
        int h = h0 + lr;
        float cv = A.ps[lr+1][w+4];
        sb[(size_t)(h+1)*SROW + (w+4)] = cv;
        float d;
        d = cv - A.ps[lr  ][w+3]; mn[0]=fminf(mn[0],d); mx[0]=fmaxf(mx[0],d);  // (-1,-1)
        d = cv - A.ps[lr+2][w+5]; mn[1]=fminf(mn[1],d); mx[1]=fmaxf(mx[1],d);  // (+1,+1)
        d = cv - A.ps[lr  ][w+4]; mn[2]=fminf(mn[2],d); mx[2]=fmaxf(mx[2],d);  // (-1, 0)
        d = cv - A.ps[lr+2][w+4]; mn[3]=fminf(mn[3],d); mx[3]=fmaxf(mx[3],d);  // (+1, 0)
        d = cv - A.ps[lr  ][w+5]; mn[4]=fminf(mn[4],d); mx[4]=fmaxf(mx[4],d);  // (-1,+1)
        d = cv - A.ps[lr+2][w+3]; mn[5]=fminf(mn[5],d); mx[5]=fmaxf(mx[5],d);  // (+1,-1)
        d = cv - A.ps[lr+1][w+5]; mn[6]=fminf(mn[6],d); mx[6]=fmaxf(mx[6],d);  // ( 0,+1)
        d = cv - A.ps[lr+1][w+3]; mn[7]=fminf(mn[7],d); mx[7]=fmaxf(mx[7],d);  // ( 0,-1)
    }
    #pragma unroll
    for (int off=32; off; off>>=1){
        #pragma unroll
        for (int q=0;q<8;q++){
            mn[q] = fminf(mn[q], __shfl_down(mn[q], off));
            mx[q] = fmaxf(mx[q], __shfl_down(mx[q], off));
        }
    }
    if (lane == 0){
        #pragma unroll
        for (int q=0;q<8;q++){ A.redmn[wv][q]=mn[q]; A.redmx[wv][q]=mx[q]; }
    }
    __syncthreads();
    int blk = b*NPART + c;
    if (tid < 8){
        pmn[(size_t)blk*8 + tid] = fminf(fminf(A.redmn[0][tid],A.redmn[1][tid]),
                                         fminf(A.redmn[2][tid],A.redmn[3][tid]));
        pmx[(size_t)blk*8 + tid] = fmaxf(fmaxf(A.redmx[0][tid],A.redmx[1][tid]),
                                         fmaxf(A.redmx[2][tid],A.redmx[3][tid]));
    }
}

// ---- Phase B: joint histogram over one 4(5)-row band. vb = b*NBAND + c ----
__device__ void phaseB(SB& Bm, int vb, const float* __restrict__ s, const float* __restrict__ cl,
                       const float* __restrict__ chp,
                       const float* __restrict__ pmn, const float* __restrict__ pmx,
                       float* __restrict__ hist)
{
    int tid = threadIdx.x, wv = tid >> 6, lane = tid & 63;
    int c = vb & (NBAND-1), b = vb >> 6;
    int h0 = c*4;
    int nr = (c == NBAND-1) ? 5 : 4;

    float4 z4 = make_float4(0.f,0.f,0.f,0.f);
    float4* lhv = (float4*)Bm.lh;
    for (int t = tid; t < 2048; t += 256) lhv[t] = z4;

    const float* sb = s + (size_t)b*SBP;
    int tot = (nr+2)*66;
    for (int t = tid; t < tot; t += 256){
        int lr = t/66, q = t - lr*66;
        *(float4*)&Bm.band[lr][q*4] = *(const float4*)(sb + (size_t)(h0+lr)*SROW + q*4);
    }

    float mnA=INFINITY, mxA=-INFINITY, mnB=INFINITY, mxB=-INFINITY;
    for (int t = lane; t < NPART; t += 64){
        const float* pn = pmn + ((size_t)(b*NPART + t))*8;
        const float* px = pmx + ((size_t)(b*NPART + t))*8;
        mnA = fminf(mnA, pn[2*wv]);   mxA = fmaxf(mxA, px[2*wv]);
        mnB = fminf(mnB, pn[2*wv+1]); mxB = fmaxf(mxB, px[2*wv+1]);
    }
    #pragma unroll
    for (int off=32; off; off>>=1){
        mnA = fminf(mnA, __shfl_down(mnA, off)); mxA = fmaxf(mxA, __shfl_down(mxA, off));
        mnB = fminf(mnB, __shfl_down(mnB, off)); mxB = fmaxf(mxB, __shfl_down(mxB, off));
    }
    mnA = __shfl(mnA, 0); mxA = __shfl(mxA, 0);
    mnB = __shfl(mnB, 0); mxB = __shfl(mxB, 0);
    float lo = cl[0], hi = chp[0];
    float mn0 = fminf(fmaxf(mnA, lo), hi), mx0 = fminf(fmaxf(mxA, lo), hi);
    float mn1 = fminf(fmaxf(mnB, lo), hi), mx1 = fminf(fmaxf(mxB, lo), hi);
    float cd0 = (mx0-mn0)*0.125f;
    float cd1 = (mx1-mn1)*0.125f;
    float m0[9], m1[9];
    #pragma unroll
    for (int i=0;i<9;i++){
        m0[i] = __fadd_rn(__fmul_rn((float)i, cd0), mn0);   // match ref: mul then add, no fma
        m1[i] = __fadd_rn(__fmul_rn((float)i, cd1), mn1);
    }
    int g = b*4 + wv;
    int dh, dw; group_off(wv, dh, dw);
    float* lhg = Bm.lh + wv*2048 + (lane & 31);
    __syncthreads();

    int npx = nr*257;
    for (int p = lane; p < npx; p += 64){
        int lrr = p/257;
        int w = p - lrr*257;
        float cc = Bm.band[lrr+1][w+4];
        float v0 = fminf(fmaxf(cc - Bm.band[lrr+1+dh][w+4+dw], lo), hi);
        float v1 = fminf(fmaxf(cc - Bm.band[lrr+1-dh][w+4-dw], lo), hi);
        unsigned b0=0, b1=0;
        #pragma unroll
        for (int i=0;i<8;i++){
            b0 |= (v0>=m0[i] && v0<=m0[i+1]) ? (1u<<i) : 0u;  // boundary values hit 2 bins, like ref
            b1 |= (v1>=m1[i] && v1<=m1[i+1]) ? (1u<<i) : 0u;
        }
        float pr = v0*v1;
        unsigned bb0=b0;
        while (bb0){
            int i = __ffs(bb0)-1; bb0 &= bb0-1;
            unsigned bb1=b1;
            while (bb1){
                int j = __ffs(bb1)-1; bb1 &= bb1-1;
                atomicAdd(&lhg[(i*8+j)*32], pr);
            }
        }
    }
    __syncthreads();
    float acc = 0.f;
    #pragma unroll
    for (int r=0;r<32;r++) acc += Bm.lh[(wv*64 + lane)*32 + ((lane + r)&31)];
    if (acc != 0.f) atomicAdd(&hist[g*64 + lane], acc);
}

// ---- Phase C: stats (recompute, no hloc) + fold + 4 output rows. vc = b*NBAND + ch ----
__device__ void phaseC(SC& Cm, int vc, const float* __restrict__ hist,
                    const float* __restrict__ pmn, const float* __restrict__ pmx,
                    const float* __restrict__ cl, const float* __restrict__ chp,
                    const float* __restrict__ we, const float* __restrict__ be,
                    const float* __restrict__ wc, const float* __restrict__ bc,
                    const float* __restrict__ wf, const float* __restrict__ bf,
                    float* __restrict__ out)
{
    int tid = threadIdx.x, wv = tid >> 6, lane = tid & 63;
    int ch = vc & (NBAND-1), b = vc >> 6;
    if (tid < 144) Cm.wfl[tid] = wf[tid];

    float rmn[8], rmx[8];
    #pragma unroll
    for (int q=0;q<8;q++){ rmn[q]=INFINITY; rmx[q]=-INFINITY; }
    for (int t = tid; t < NPART; t += 256){
        const float* pn = pmn + ((size_t)(b*NPART + t))*8;
        const float* px = pmx + ((size_t)(b*NPART + t))*8;
        #pragma unroll
        for (int q=0;q<8;q++){ rmn[q]=fminf(rmn[q],pn[q]); rmx[q]=fmaxf(rmx[q],px[q]); }
    }
    #pragma unroll
    for (int off=32; off; off>>=1){
        #pragma unroll
        for (int q=0;q<8;q++){
            rmn[q] = fminf(rmn[q], __shfl_down(rmn[q], off));
            rmx[q] = fmaxf(rmx[q], __shfl_down(rmx[q], off));
        }
    }
    if (lane == 0){
        #pragma unroll
        for (int q=0;q<8;q++){ Cm.wred[wv][q]=rmn[q]; Cm.wred[wv][8+q]=rmx[q]; }
    }
    // hist sum partial
    float ps = 0.f;
    for (int t = tid; t < 4096; t += 256) ps += hist[t];
    #pragma unroll
    for (int off=32; off; off>>=1) ps += __shfl_down(ps, off);
    if (lane == 0) Cm.sred[wv] = ps;
    __syncthreads();

    if (tid < 8)
        Cm.gmn[tid] = fminf(fminf(Cm.wred[0][tid],Cm.wred[1][tid]), fminf(Cm.wred[2][tid],Cm.wred[3][tid]));
    else if (tid < 16){
        int q = tid-8;
        Cm.gmx[q] = fmaxf(fmaxf(Cm.wred[0][8+q],Cm.wred[1][8+q]), fmaxf(Cm.wred[2][8+q],Cm.wred[3][8+q]));
    }
    float S = Cm.sred[0]+Cm.sred[1]+Cm.sred[2]+Cm.sred[3];
    for (int t = tid; t < 256; t += 256)
        Cm.hh[t>>6][t&63] = hist[b*256 + t] / S;
    __syncthreads();

    float lo = cl[0], hi = chp[0];
    float mn0 = fminf(fmaxf(Cm.gmn[2*wv  ], lo), hi), mx0 = fminf(fmaxf(Cm.gmx[2*wv  ], lo), hi);
    float mn1 = fminf(fmaxf(Cm.gmn[2*wv+1], lo), hi), mx1 = fminf(fmaxf(Cm.gmx[2*wv+1], lo), hi);
    float lvl0 = __fadd_rn(__fmul_rn(1.0f,(mx0-mn0)*0.125f), mn0);
    float lvl1 = __fadd_rn(__fmul_rn(1.0f,(mx1-mn1)*0.125f), mn1);
    if (lane == 0){ Cm.glvl[2*wv] = lvl0; Cm.glvl[2*wv+1] = lvl1; }

    const float* hhg = Cm.hh[wv];
    float pm = 0.f;
    for (int e = lane; e < 3584; e += 64){
        int ij = e/56, o = e - ij*56;
        float a = expand_a(ij, o, lvl0, lvl1, hhg, we, be);
        int lo_ = (32*o+6)/7, hi_ = (32*o+31)/7;
        pm += a * (float)(4*(hi_-lo_+1));
    }
    #pragma unroll
    for (int off=32; off; off>>=1) pm += __shfl_down(pm, off);
    pm = __shfl(pm, 0);
    float mean = pm * (1.0f/65536.0f);
    float pv = 0.f;
    for (int e = lane; e < 3584; e += 64){
        int ij = e/56, o = e - ij*56;
        float a = expand_a(ij, o, lvl0, lvl1, hhg, we, be);
        int lo_ = (32*o+6)/7, hi_ = (32*o+31)/7;
        float d = a - mean;
        pv += d*d * (float)(4*(hi_-lo_+1));
    }
    #pragma unroll
    for (int off=32; off; off>>=1) pv += __shfl_down(pv, off);
    pv = __shfl(pv, 0);
    if (lane == 0){
        Cm.gstat[wv*2+0] = mean;
        Cm.gstat[wv*2+1] = 1.0f / sqrtf(pv * (1.0f/65536.0f) + 1e-5f);
    }
    __syncthreads();

    // fold w9 rows [rm, rp] (output rows [4ch, 4ch+4), yy>>2 in [ch-1, ch+1])
    int rm = (ch-1 > 0) ? (ch-1) : 0;
    int rp = (ch+1 < 63) ? (ch+1) : 63;
    int ne = (rp-rm+1)*56;
    for (int e = tid; e < ne; e += 256){
        int rr = e/56, sxc = e - rr*56;
        int ij = rm + rr;
        float hn[4];
        #pragma unroll
        for (int k=0;k<4;k++){
            float a = expand_a(ij, sxc, Cm.glvl[2*k], Cm.glvl[2*k+1], Cm.hh[k], we, be);
            hn[k] = (a - Cm.gstat[2*k]) * Cm.gstat[2*k+1];
        }
        float w9v[9] = {0,0,0,0,0,0,0,0,0};
        #pragma unroll
        for (int c2=0;c2<16;c2++){
            float hv = bc[c2];
            #pragma unroll
            for (int k=0;k<4;k++) hv += wc[c2*4+k]*hn[k];
            hv = leaky(hv);
            #pragma unroll
            for (int t=0;t<9;t++) w9v[t] += Cm.wfl[c2*9+t]*hv;
        }
        #pragma unroll
        for (int t=0;t<9;t++) Cm.w9l[rr*504 + t*56 + sxc] = w9v[t];
    }
    __syncthreads();

    float bf0 = bf[0];
    int x = tid;
    int sxm = ((x-1)*7) >> 5;
    int sx0 = (x*7) >> 5;
    int sxp = ((x+1)*7) >> 5;
    for (int yo=0; yo<4; ++yo){
        int y = ch*4 + yo;
        float acc = bf0;
        #pragma unroll
        for (int dy=0; dy<3; ++dy){
            int yy = y + dy - 1;
            if ((unsigned)yy >= 256u) continue;
            const float* wr = &Cm.w9l[((yy>>2) - rm)*504 + dy*3*56];
            if (x >= 1)   acc += wr[sxm];
                          acc += wr[56 + sx0];
            if (x <= 254) acc += wr[2*56 + sxp];
        }
        out[((size_t)(b*256 + y))*256 + x] = leaky(acc);
    }
}

// ---- Fused persistent kernel ----
__global__ __launch_bounds__(256, 4) void fused(int nblk, unsigned* __restrict__ bar,
                    const float* __restrict__ x, float* __restrict__ s,
                    float* __restrict__ pmn, float* __restrict__ pmx, float* __restrict__ hist,
                    const float* __restrict__ cl, const float* __restrict__ chp,
                    const float* __restrict__ we, const float* __restrict__ be,
                    const float* __restrict__ wc, const float* __restrict__ bc,
                    const float* __restrict__ wf, const float* __restrict__ bf,
                    float* __restrict__ out)
{
    __shared__ SU sm;
    int bid = blockIdx.x;

    for (int v = bid; v < NVIRT; v += nblk){
        __syncthreads();
        phaseA(sm.a, v, x, s, pmn, pmx, hist);
    }
    grid_barrier(bar, 0, nblk);

    for (int v = bid; v < NVIRT; v += nblk){
        __syncthreads();
        phaseB(sm.b, v, s, cl, chp, pmn, pmx, hist);
    }
    grid_barrier(bar, 1, nblk);

    for (int v = bid; v < NVIRT; v += nblk){
        __syncthreads();
        phaseC(sm.c, v, hist, pmn, pmx, cl, chp, we, be, wc, bc, wf, bf, out);
    }
}

extern "C" void kernel_launch(void* const* d_in, const int* in_sizes, int n_in,
                              void* d_out, int out_size, void* d_ws, size_t ws_size,
                              hipStream_t stream){
    const float* x  = (const float*)d_in[0];
    const float* cl = (const float*)d_in[1];
    const float* ch = (const float*)d_in[2];
    const float* we = (const float*)d_in[3];
    const float* be = (const float*)d_in[4];
    const float* wc = (const float*)d_in[5];
    const float* bc = (const float*)d_in[6];
    const float* wf = (const float*)d_in[7];
    const float* bf = (const float*)d_in[8];
    float* out = (float*)d_out;

    float* s = (float*)d_ws;
    size_t off = (size_t)BATCH*SBP;
    float* pmn  = s + off; off += (size_t)BATCH*NPART*8;
    float* pmx  = s + off; off += (size_t)BATCH*NPART*8;
    float* hist = s + off; off += 4096;
    unsigned* bar = (unsigned*)(s + off); off += 16;

    // Residency-derived grid. The barrier deadlocks unless ALL blocks are co-resident,
    // so derive capacity from queries (handles partitioned devices); fall back tiny.
    static int cached_nblk = 0;
    if (cached_nblk == 0){
        int perCU = 0, nCU = 0, dev = 0;
        hipError_t e1 = hipGetDevice(&dev);
        hipError_t e2 = hipOccupancyMaxActiveBlocksPerMultiprocessor(&perCU, fused, 256, 0);
        hipError_t e3 = hipDeviceGetAttribute(&nCU, hipDeviceAttributeMultiprocessorCount, dev);
        if (e1 == hipSuccess && e2 == hipSuccess && e3 == hipSuccess && perCU >= 1 && nCU >= 1){
            long cap = (long)perCU * (long)nCU;
            cached_nblk = (cap > NVIRT) ? NVIRT : (int)cap;
        } else {
            cached_nblk = 32;   // co-resident on any partition; grid-stride keeps it correct
        }
    }
    int nblk = cached_nblk;

    hipMemsetAsync(bar, 0, 8*sizeof(unsigned), stream);
    fused<<<nblk, 256, 0, stream>>>(nblk, bar, x, s, pmn, pmx, hist,
                                    cl, ch, we, be, wc, bc, wf, bf, out);
}

// Round 8
// 220.159 us; speedup vs baseline: 1.2445x; 1.2445x over previous
//
#include <hip/hip_runtime.h>
#include <stdint.h>
#include <math.h>

#define HH 256
#define WW 256
#define BATCH 16
#define HP 257            // pooled field is 257x257
#define SROW 264          // padded row stride (multiple of 4 -> vec4 rows)
#define SH 259            // padded rows (1 zero row top/bottom)
#define SBP (SH*SROW)     // per-batch padded s size
#define NBAND 64          // 4-row bands per batch (all three kernels)
#define NPART 64          // minmax partial sets per batch (one per A band)

// s layout: s[b][r][c], r=0..258, c=0..263. Core: pooled(h,w) at r=h+1, c=w+4.
// Pads: r=0, r=258 zero rows; cols 0..3 and 261..263 zero. Core cols 4..260.

__device__ __forceinline__ float leaky(float v){ return v >= 0.f ? v : 0.01f*v; }

__device__ __forceinline__ void group_off(int k, int& dh, int& dw){
    dh = (k == 3) ? 0 : -1;
    dw = (k == 3) ? 1 : (k - 1);
}

// expand+leaky activation recompute (textually identical to the stored-hloc version)
__device__ __forceinline__ float expand_a(int ij, int o, float lvl0, float lvl1,
                                          const float* hh_g,
                                          const float* __restrict__ we,
                                          const float* __restrict__ be){
    int i = ij>>3, j = ij&7;
    float f0 = __fmul_rn((float)(i+1), lvl0);
    float f1 = __fmul_rn((float)(j+1), lvl1);
    float f2 = hh_g[ij];
    return leaky(f0*we[o*3+0] + f1*we[o*3+1] + f2*we[o*3+2] + be[o]);
}

// ---- KA: 4-row band pool -> s + 8-diff minmax partials. grid (64, BATCH). ----
__global__ __launch_bounds__(256, 4) void ka(const float* __restrict__ x, float* __restrict__ s,
                                             float* __restrict__ pmn, float* __restrict__ pmx,
                                             float* __restrict__ hist){
    __shared__ __align__(16) float xs[8][264];   // X rows h0-2 .. h0+nr (chan-summed, col+4)
    __shared__ __align__(16) float ps[7][264];   // pooled rows h0-1 .. h0+nr (col+4)
    __shared__ float redmn[4][8], redmx[4][8];
    int c = blockIdx.x, b = blockIdx.y;
    int tid = threadIdx.x, wv = tid >> 6, lane = tid & 63;
    int h0 = c*4;
    int nr = (c == NBAND-1) ? 5 : 4;

    if (c == 0 && b == 0){
        for (int t = tid; t < 4096; t += 256) hist[t] = 0.f;
    }
    float* sb = s + (size_t)b*SBP;
    for (int t = tid; t < nr*7; t += 256){
        int rr = t/7, k = t%7;
        int col = (k < 4) ? k : (257 + k);      // 0..3, 261..263
        sb[(size_t)(h0+1+rr)*SROW + col] = 0.f;
    }
    if (c == 0){        for (int t = tid; t < SROW; t += 256) sb[t] = 0.f; }
    if (c == NBAND-1){  for (int t = tid; t < SROW; t += 256) sb[(size_t)258*SROW + t] = 0.f; }

    // stage channel-summed X rows h0-2 .. h0+nr, cols -4..259 zero-padded, vec4
    const float* xb = x + (size_t)b*3*HH*WW;
    int nxr = nr + 3;
    for (int t = tid; t < nxr*66; t += 256){
        int i = t/66, q = t - i*66;
        int r = h0 - 2 + i;
        float4 v = make_float4(0.f, 0.f, 0.f, 0.f);
        if (q >= 1 && q <= 64 && (unsigned)r < 256u){
            const float* base = xb + (size_t)r*WW + (q-1)*4;
            float4 a = *(const float4*)(base);
            float4 d = *(const float4*)(base + HH*WW);
            float4 e = *(const float4*)(base + 2*HH*WW);
            v.x = a.x + d.x + e.x;
            v.y = a.y + d.y + e.y;
            v.z = a.z + d.z + e.z;
            v.w = a.w + d.w + e.w;
        }
        *(float4*)&xs[i][q*4] = v;
    }
    __syncthreads();

    // pooled rows j=0..nr+1 (pooled row h = h0-1+j); zero outside [0,257)
    int np = (nr+2)*257;
    for (int t = tid; t < np; t += 256){
        int j = t/257, w = t - j*257;
        int h = h0 - 1 + j;
        float v = 0.f;
        if ((unsigned)h < (unsigned)HP)
            v = 0.25f*(xs[j][w+3] + xs[j][w+4] + xs[j+1][w+3] + xs[j+1][w+4]);
        ps[j][w+4] = v;
    }
    for (int t = tid; t < (nr+2)*7; t += 256){
        int j = t/7, k = t%7;
        ps[j][(k < 4) ? k : (257 + k)] = 0.f;
    }
    __syncthreads();

    float mn[8], mx[8];
    #pragma unroll
    for (int q=0;q<8;q++){ mn[q]=INFINITY; mx[q]=-INFINITY; }
    int nd = nr*257;
    for (int t = tid; t < nd; t += 256){
        int lr = t/257, w = t - lr*257;
        int h = h0 + lr;
        float cv = ps[lr+1][w+4];
        sb[(size_t)(h+1)*SROW + (w+4)] = cv;
        float d;
        d = cv - ps[lr  ][w+3]; mn[0]=fminf(mn[0],d); mx[0]=fmaxf(mx[0],d);  // (-1,-1)
        d = cv - ps[lr+2][w+5]; mn[1]=fminf(mn[1],d); mx[1]=fmaxf(mx[1],d);  // (+1,+1)
        d = cv - ps[lr  ][w+4]; mn[2]=fminf(mn[2],d); mx[2]=fmaxf(mx[2],d);  // (-1, 0)
        d = cv - ps[lr+2][w+4]; mn[3]=fminf(mn[3],d); mx[3]=fmaxf(mx[3],d);  // (+1, 0)
        d = cv - ps[lr  ][w+5]; mn[4]=fminf(mn[4],d); mx[4]=fmaxf(mx[4],d);  // (-1,+1)
        d = cv - ps[lr+2][w+3]; mn[5]=fminf(mn[5],d); mx[5]=fmaxf(mx[5],d);  // (+1,-1)
        d = cv - ps[lr+1][w+5]; mn[6]=fminf(mn[6],d); mx[6]=fmaxf(mx[6],d);  // ( 0,+1)
        d = cv - ps[lr+1][w+3]; mn[7]=fminf(mn[7],d); mx[7]=fmaxf(mx[7],d);  // ( 0,-1)
    }
    #pragma unroll
    for (int off=32; off; off>>=1){
        #pragma unroll
        for (int q=0;q<8;q++){
            mn[q] = fminf(mn[q], __shfl_down(mn[q], off));
            mx[q] = fmaxf(mx[q], __shfl_down(mx[q], off));
        }
    }
    if (lane == 0){
        #pragma unroll
        for (int q=0;q<8;q++){ redmn[wv][q]=mn[q]; redmx[wv][q]=mx[q]; }
    }
    __syncthreads();
    int blk = b*NPART + c;
    if (tid < 8){
        pmn[(size_t)blk*8 + tid] = fminf(fminf(redmn[0][tid],redmn[1][tid]),
                                         fminf(redmn[2][tid],redmn[3][tid]));
        pmx[(size_t)blk*8 + tid] = fmaxf(fmaxf(redmx[0][tid],redmx[1][tid]),
                                         fmaxf(redmx[2][tid],redmx[3][tid]));
    }
}

// ---- KB: joint histogram over one 4(5)-row band. grid (64, BATCH). ----
__global__ __launch_bounds__(256, 4) void kb(const float* __restrict__ s, const float* __restrict__ cl,
                                             const float* __restrict__ chp,
                                             const float* __restrict__ pmn, const float* __restrict__ pmx,
                                             float* __restrict__ hist){
    __shared__ __align__(16) float lh[4*64*32];   // [group][bin][replica] = 32 KB
    __shared__ __align__(16) float band[7][264];  // s rows h0 .. h0+nr+1
    int c = blockIdx.x, b = blockIdx.y;
    int tid = threadIdx.x, wv = tid >> 6, lane = tid & 63;
    int h0 = c*4;
    int nr = (c == NBAND-1) ? 5 : 4;

    float4 z4 = make_float4(0.f,0.f,0.f,0.f);
    float4* lhv = (float4*)lh;
    for (int t = tid; t < 2048; t += 256) lhv[t] = z4;

    const float* sb = s + (size_t)b*SBP;
    int tot = (nr+2)*66;
    for (int t = tid; t < tot; t += 256){
        int lr = t/66, q = t - lr*66;
        *(float4*)&band[lr][q*4] = *(const float4*)(sb + (size_t)(h0+lr)*SROW + q*4);
    }

    float mnA=INFINITY, mxA=-INFINITY, mnB=INFINITY, mxB=-INFINITY;
    for (int t = lane; t < NPART; t += 64){
        const float* pn = pmn + ((size_t)(b*NPART + t))*8;
        const float* px = pmx + ((size_t)(b*NPART + t))*8;
        mnA = fminf(mnA, pn[2*wv]);   mxA = fmaxf(mxA, px[2*wv]);
        mnB = fminf(mnB, pn[2*wv+1]); mxB = fmaxf(mxB, px[2*wv+1]);
    }
    #pragma unroll
    for (int off=32; off; off>>=1){
        mnA = fminf(mnA, __shfl_down(mnA, off)); mxA = fmaxf(mxA, __shfl_down(mxA, off));
        mnB = fminf(mnB, __shfl_down(mnB, off)); mxB = fmaxf(mxB, __shfl_down(mxB, off));
    }
    mnA = __shfl(mnA, 0); mxA = __shfl(mxA, 0);
    mnB = __shfl(mnB, 0); mxB = __shfl(mxB, 0);
    float lo = cl[0], hi = chp[0];
    float mn0 = fminf(fmaxf(mnA, lo), hi), mx0 = fminf(fmaxf(mxA, lo), hi);
    float mn1 = fminf(fmaxf(mnB, lo), hi), mx1 = fminf(fmaxf(mxB, lo), hi);
    float cd0 = (mx0-mn0)*0.125f;
    float cd1 = (mx1-mn1)*0.125f;
    float m0[9], m1[9];
    #pragma unroll
    for (int i=0;i<9;i++){
        m0[i] = __fadd_rn(__fmul_rn((float)i, cd0), mn0);   // match ref: mul then add, no fma
        m1[i] = __fadd_rn(__fmul_rn((float)i, cd1), mn1);
    }
    int g = b*4 + wv;
    int dh, dw; group_off(wv, dh, dw);
    float* lhg = lh + wv*2048 + (lane & 31);
    __syncthreads();

    int npx = nr*257;
    for (int p = lane; p < npx; p += 64){
        int lrr = p/257;
        int w = p - lrr*257;
        float cc = band[lrr+1][w+4];
        float v0 = fminf(fmaxf(cc - band[lrr+1+dh][w+4+dw], lo), hi);
        float v1 = fminf(fmaxf(cc - band[lrr+1-dh][w+4-dw], lo), hi);
        unsigned b0=0, b1=0;
        #pragma unroll
        for (int i=0;i<8;i++){
            b0 |= (v0>=m0[i] && v0<=m0[i+1]) ? (1u<<i) : 0u;  // boundary values hit 2 bins, like ref
            b1 |= (v1>=m1[i] && v1<=m1[i+1]) ? (1u<<i) : 0u;
        }
        float pr = v0*v1;
        unsigned bb0=b0;
        while (bb0){
            int i = __ffs(bb0)-1; bb0 &= bb0-1;
            unsigned bb1=b1;
            while (bb1){
                int j = __ffs(bb1)-1; bb1 &= bb1-1;
                atomicAdd(&lhg[(i*8+j)*32], pr);
            }
        }
    }
    __syncthreads();
    float acc = 0.f;
    #pragma unroll
    for (int r=0;r<32;r++) acc += lh[(wv*64 + lane)*32 + ((lane + r)&31)];
    if (acc != 0.f) atomicAdd(&hist[g*64 + lane], acc);
}

// ---- KC: stats (recompute, no hloc) + fold + 4 output rows. grid (64, BATCH). ----
__global__ __launch_bounds__(256, 4) void kc(const float* __restrict__ hist,
                    const float* __restrict__ pmn, const float* __restrict__ pmx,
                    const float* __restrict__ cl, const float* __restrict__ chp,
                    const float* __restrict__ we, const float* __restrict__ be,
                    const float* __restrict__ wc, const float* __restrict__ bc,
                    const float* __restrict__ wf, const float* __restrict__ bf,
                    float* __restrict__ out){
    __shared__ float hh[4][64];
    __shared__ float w9l[3*9*56];
    __shared__ float wfl[144];
    __shared__ float wred[4][16];
    __shared__ float gmn[8], gmx[8];
    __shared__ float gstat[8];
    __shared__ float glvl[8];
    __shared__ float sred[4];
    int ch = blockIdx.x, b = blockIdx.y;
    int tid = threadIdx.x, wv = tid >> 6, lane = tid & 63;
    if (tid < 144) wfl[tid] = wf[tid];

    float rmn[8], rmx[8];
    #pragma unroll
    for (int q=0;q<8;q++){ rmn[q]=INFINITY; rmx[q]=-INFINITY; }
    for (int t = tid; t < NPART; t += 256){
        const float* pn = pmn + ((size_t)(b*NPART + t))*8;
        const float* px = pmx + ((size_t)(b*NPART + t))*8;
        #pragma unroll
        for (int q=0;q<8;q++){ rmn[q]=fminf(rmn[q],pn[q]); rmx[q]=fmaxf(rmx[q],px[q]); }
    }
    #pragma unroll
    for (int off=32; off; off>>=1){
        #pragma unroll
        for (int q=0;q<8;q++){
            rmn[q] = fminf(rmn[q], __shfl_down(rmn[q], off));
            rmx[q] = fmaxf(rmx[q], __shfl_down(rmx[q], off));
        }
    }
    if (lane == 0){
        #pragma unroll
        for (int q=0;q<8;q++){ wred[wv][q]=rmn[q]; wred[wv][8+q]=rmx[q]; }
    }
    // hist sum partial
    float ps = 0.f;
    for (int t = tid; t < 4096; t += 256) ps += hist[t];
    #pragma unroll
    for (int off=32; off; off>>=1) ps += __shfl_down(ps, off);
    if (lane == 0) sred[wv] = ps;
    __syncthreads();

    if (tid < 8)
        gmn[tid] = fminf(fminf(wred[0][tid],wred[1][tid]), fminf(wred[2][tid],wred[3][tid]));
    else if (tid < 16){
        int q = tid-8;
        gmx[q] = fmaxf(fmaxf(wred[0][8+q],wred[1][8+q]), fmaxf(wred[2][8+q],wred[3][8+q]));
    }
    float S = sred[0]+sred[1]+sred[2]+sred[3];
    for (int t = tid; t < 256; t += 256)
        hh[t>>6][t&63] = hist[b*256 + t] / S;
    __syncthreads();

    float lo = cl[0], hi = chp[0];
    float mn0 = fminf(fmaxf(gmn[2*wv  ], lo), hi), mx0 = fminf(fmaxf(gmx[2*wv  ], lo), hi);
    float mn1 = fminf(fmaxf(gmn[2*wv+1], lo), hi), mx1 = fminf(fmaxf(gmx[2*wv+1], lo), hi);
    float lvl0 = __fadd_rn(__fmul_rn(1.0f,(mx0-mn0)*0.125f), mn0);
    float lvl1 = __fadd_rn(__fmul_rn(1.0f,(mx1-mn1)*0.125f), mn1);
    if (lane == 0){ glvl[2*wv] = lvl0; glvl[2*wv+1] = lvl1; }

    const float* hhg = hh[wv];
    float pm = 0.f;
    for (int e = lane; e < 3584; e += 64){
        int ij = e/56, o = e - ij*56;
        float a = expand_a(ij, o, lvl0, lvl1, hhg, we, be);
        int lo_ = (32*o+6)/7, hi_ = (32*o+31)/7;
        pm += a * (float)(4*(hi_-lo_+1));
    }
    #pragma unroll
    for (int off=32; off; off>>=1) pm += __shfl_down(pm, off);
    pm = __shfl(pm, 0);
    float mean = pm * (1.0f/65536.0f);
    float pv = 0.f;
    for (int e = lane; e < 3584; e += 64){
        int ij = e/56, o = e - ij*56;
        float a = expand_a(ij, o, lvl0, lvl1, hhg, we, be);
        int lo_ = (32*o+6)/7, hi_ = (32*o+31)/7;
        float d = a - mean;
        pv += d*d * (float)(4*(hi_-lo_+1));
    }
    #pragma unroll
    for (int off=32; off; off>>=1) pv += __shfl_down(pv, off);
    pv = __shfl(pv, 0);
    if (lane == 0){
        gstat[wv*2+0] = mean;
        gstat[wv*2+1] = 1.0f / sqrtf(pv * (1.0f/65536.0f) + 1e-5f);
    }
    __syncthreads();

    // fold w9 rows [rm, rp] (output rows [4ch, 4ch+4), yy>>2 in [ch-1, ch+1])
    int rm = (ch-1 > 0) ? (ch-1) : 0;
    int rp = (ch+1 < 63) ? (ch+1) : 63;
    int ne = (rp-rm+1)*56;
    for (int e = tid; e < ne; e += 256){
        int rr = e/56, sxc = e - rr*56;
        int ij = rm + rr;
        float hn[4];
        #pragma unroll
        for (int k=0;k<4;k++){
            float a = expand_a(ij, sxc, glvl[2*k], glvl[2*k+1], hh[k], we, be);
            hn[k] = (a - gstat[2*k]) * gstat[2*k+1];
        }
        float w9v[9] = {0,0,0,0,0,0,0,0,0};
        #pragma unroll
        for (int c2=0;c2<16;c2++){
            float hv = bc[c2];
            #pragma unroll
            for (int k=0;k<4;k++) hv += wc[c2*4+k]*hn[k];
            hv = leaky(hv);
            #pragma unroll
            for (int t=0;t<9;t++) w9v[t] += wfl[c2*9+t]*hv;
        }
        #pragma unroll
        for (int t=0;t<9;t++) w9l[rr*504 + t*56 + sxc] = w9v[t];
    }
    __syncthreads();

    float bf0 = bf[0];
    int x = tid;
    int sxm = ((x-1)*7) >> 5;
    int sx0 = (x*7) >> 5;
    int sxp = ((x+1)*7) >> 5;
    for (int yo=0; yo<4; ++yo){
        int y = ch*4 + yo;
        float acc = bf0;
        #pragma unroll
        for (int dy=0; dy<3; ++dy){
            int yy = y + dy - 1;
            if ((unsigned)yy >= 256u) continue;
            const float* wr = &w9l[((yy>>2) - rm)*504 + dy*3*56];
            if (x >= 1)   acc += wr[sxm];
                          acc += wr[56 + sx0];
            if (x <= 254) acc += wr[2*56 + sxp];
        }
        out[((size_t)(b*256 + y))*256 + x] = leaky(acc);
    }
}

extern "C" void kernel_launch(void* const* d_in, const int* in_sizes, int n_in,
                              void* d_out, int out_size, void* d_ws, size_t ws_size,
                              hipStream_t stream){
    const float* x  = (const float*)d_in[0];
    const float* cl = (const float*)d_in[1];
    const float* ch = (const float*)d_in[2];
    const float* we = (const float*)d_in[3];
    const float* be = (const float*)d_in[4];
    const float* wc = (const float*)d_in[5];
    const float* bc = (const float*)d_in[6];
    const float* wf = (const float*)d_in[7];
    const float* bf = (const float*)d_in[8];
    float* out = (float*)d_out;

    float* s = (float*)d_ws;
    size_t off = (size_t)BATCH*SBP;
    float* pmn  = s + off; off += (size_t)BATCH*NPART*8;
    float* pmx  = s + off; off += (size_t)BATCH*NPART*8;
    float* hist = s + off; off += 4096;

    ka<<<dim3(NBAND,BATCH), 256, 0, stream>>>(x, s, pmn, pmx, hist);
    kb<<<dim3(NBAND,BATCH), 256, 0, stream>>>(s, cl, ch, pmn, pmx, hist);
    kc<<<dim3(NBAND,BATCH), 256, 0, stream>>>(hist, pmn, pmx, cl, ch, we, be, wc, bc, wf, bf, out);
}

// Round 10
// 150.447 us; speedup vs baseline: 1.8212x; 1.4634x over previous
//
#include <hip/hip_runtime.h>
#include <stdint.h>
#include <math.h>

#define HH 256
#define WW 256
#define BATCH 16
#define HP 257            // pooled field is 257x257
#define SROW 264          // padded row stride (multiple of 4 -> vec4 rows)
#define SH 259            // padded rows (1 zero row top/bottom)
#define SBP (SH*SROW)     // per-batch padded s size
#define NPART 32          // minmax partial sets per batch (one per k1 band)
#define NSTAT 272         // per-batch stats: glvl[8] + gstat[8] + hh[4][64]

// s layout: s[b][r][c], r=0..258, c=0..263. Core: pooled(h,w) at r=h+1, c=w+4.
// Pads: r=0, r=258 zero rows; cols 0..3 and 261..263 zero. Core cols 4..260.

__device__ __forceinline__ float leaky(float v){ return v >= 0.f ? v : 0.01f*v; }

__device__ __forceinline__ void group_off(int k, int& dh, int& dw){
    dh = (k == 3) ? 0 : -1;
    dw = (k == 3) ? 1 : (k - 1);
}

// expand+leaky activation (verified in R8: identical numerics to stored-hloc version)
__device__ __forceinline__ float expand_a(int ij, int o, float lvl0, float lvl1,
                                          const float* hh_g,
                                          const float* __restrict__ we,
                                          const float* __restrict__ be){
    int i = ij>>3, j = ij&7;
    float f0 = __fmul_rn((float)(i+1), lvl0);
    float f1 = __fmul_rn((float)(j+1), lvl1);
    float f2 = hh_g[ij];
    return leaky(f0*we[o*3+0] + f1*we[o*3+1] + f2*we[o*3+2] + be[o]);
}

// ---- K1 (R5-verified): band pool -> s + 8-diff minmax partials. grid (32, BATCH). ----
__global__ __launch_bounds__(256) void k1(const float* __restrict__ x, float* __restrict__ s,
                                          float* __restrict__ pmn, float* __restrict__ pmx,
                                          float* __restrict__ hist){
    __shared__ __align__(16) float xs[12][264];   // X rows h0-2 .. h0+9 (chan-summed, col+4)
    __shared__ __align__(16) float ps[11][264];   // pooled rows h0-1 .. h0+nr (col+4)
    __shared__ float redmn[4][8], redmx[4][8];
    int c = blockIdx.x, b = blockIdx.y;
    int tid = threadIdx.x, wv = tid >> 6, lane = tid & 63;
    int h0 = c*8;
    int nr = (c == 31) ? 9 : 8;

    if (c == 0 && b == 0){
        for (int t = tid; t < 4096; t += 256) hist[t] = 0.f;
    }
    float* sb = s + (size_t)b*SBP;
    for (int t = tid; t < nr*7; t += 256){
        int rr = t/7, k = t%7;
        int col = (k < 4) ? k : (257 + k);      // 0..3, 261..263
        sb[(size_t)(h0+1+rr)*SROW + col] = 0.f;
    }
    if (c == 0){  for (int t = tid; t < SROW; t += 256) sb[t] = 0.f; }
    if (c == 31){ for (int t = tid; t < SROW; t += 256) sb[(size_t)258*SROW + t] = 0.f; }

    const float* xb = x + (size_t)b*3*HH*WW;
    for (int t = tid; t < 12*66; t += 256){
        int i = t/66, q = t - i*66;
        int r = h0 - 2 + i;
        float4 v = make_float4(0.f, 0.f, 0.f, 0.f);
        if (q >= 1 && q <= 64 && (unsigned)r < 256u){
            const float* base = xb + (size_t)r*WW + (q-1)*4;
            float4 a = *(const float4*)(base);
            float4 d = *(const float4*)(base + HH*WW);
            float4 e = *(const float4*)(base + 2*HH*WW);
            v.x = a.x + d.x + e.x;   // keep ref order: c0 + c1 + c2
            v.y = a.y + d.y + e.y;
            v.z = a.z + d.z + e.z;
            v.w = a.w + d.w + e.w;
        }
        *(float4*)&xs[i][q*4] = v;
    }
    __syncthreads();

    int np = (nr+2)*257;
    for (int t = tid; t < np; t += 256){
        int j = t/257, w = t - j*257;
        int h = h0 - 1 + j;
        float v = 0.f;
        if ((unsigned)h < (unsigned)HP)
            v = 0.25f*(xs[j][w+3] + xs[j][w+4] + xs[j+1][w+3] + xs[j+1][w+4]);
        ps[j][w+4] = v;
    }
    for (int t = tid; t < (nr+2)*7; t += 256){
        int j = t/7, k = t%7;
        ps[j][(k < 4) ? k : (257 + k)] = 0.f;   // cols 0..3, 261..263
    }
    __syncthreads();

    float mn[8], mx[8];
    #pragma unroll
    for (int q=0;q<8;q++){ mn[q]=INFINITY; mx[q]=-INFINITY; }
    int nd = nr*257;
    for (int t = tid; t < nd; t += 256){
        int lr = t/257, w = t - lr*257;
        int h = h0 + lr;
        float cv = ps[lr+1][w+4];
        sb[(size_t)(h+1)*SROW + (w+4)] = cv;
        float d;
        d = cv - ps[lr  ][w+3]; mn[0]=fminf(mn[0],d); mx[0]=fmaxf(mx[0],d);  // (-1,-1)
        d = cv - ps[lr+2][w+5]; mn[1]=fminf(mn[1],d); mx[1]=fmaxf(mx[1],d);  // (+1,+1)
        d = cv - ps[lr  ][w+4]; mn[2]=fminf(mn[2],d); mx[2]=fmaxf(mx[2],d);  // (-1, 0)
        d = cv - ps[lr+2][w+4]; mn[3]=fminf(mn[3],d); mx[3]=fmaxf(mx[3],d);  // (+1, 0)
        d = cv - ps[lr  ][w+5]; mn[4]=fminf(mn[4],d); mx[4]=fmaxf(mx[4],d);  // (-1,+1)
        d = cv - ps[lr+2][w+3]; mn[5]=fminf(mn[5],d); mx[5]=fmaxf(mx[5],d);  // (+1,-1)
        d = cv - ps[lr+1][w+5]; mn[6]=fminf(mn[6],d); mx[6]=fmaxf(mx[6],d);  // ( 0,+1)
        d = cv - ps[lr+1][w+3]; mn[7]=fminf(mn[7],d); mx[7]=fmaxf(mx[7],d);  // ( 0,-1)
    }
    #pragma unroll
    for (int off=32; off; off>>=1){
        #pragma unroll
        for (int q=0;q<8;q++){
            mn[q] = fminf(mn[q], __shfl_down(mn[q], off));
            mx[q] = fmaxf(mx[q], __shfl_down(mx[q], off));
        }
    }
    if (lane == 0){
        #pragma unroll
        for (int q=0;q<8;q++){ redmn[wv][q]=mn[q]; redmx[wv][q]=mx[q]; }
    }
    __syncthreads();
    int blk = b*NPART + c;
    if (tid < 8){
        pmn[(size_t)blk*8 + tid] = fminf(fminf(redmn[0][tid],redmn[1][tid]),
                                         fminf(redmn[2][tid],redmn[3][tid]));
        pmx[(size_t)blk*8 + tid] = fmaxf(fmaxf(redmx[0][tid],redmx[1][tid]),
                                         fmaxf(redmx[2][tid],redmx[3][tid]));
    }
}

// ---- K2 (R5-verified): joint histogram over 4-row bands. grid (64, BATCH). ----
__global__ __launch_bounds__(256) void k2(const float* __restrict__ s, const float* __restrict__ cl,
                                          const float* __restrict__ chp,
                                          const float* __restrict__ pmn, const float* __restrict__ pmx,
                                          float* __restrict__ hist){
    __shared__ __align__(16) float lh[4*64*32];   // [group][bin][replica] = 32 KB
    __shared__ __align__(16) float band[7][264];  // s rows h0 .. h0+nr+1
    int c = blockIdx.x, b = blockIdx.y;
    int tid = threadIdx.x, wv = tid >> 6, lane = tid & 63;
    int h0 = c*4;
    int nr = (c == 63) ? 5 : 4;

    float4 z4 = make_float4(0.f,0.f,0.f,0.f);
    float4* lhv = (float4*)lh;
    for (int t = tid; t < 2048; t += 256) lhv[t] = z4;

    const float* sb = s + (size_t)b*SBP;
    int tot = (nr+2)*66;
    for (int t = tid; t < tot; t += 256){
        int lr = t/66, q = t - lr*66;
        *(float4*)&band[lr][q*4] = *(const float4*)(sb + (size_t)(h0+lr)*SROW + q*4);
    }

    float mnA=INFINITY, mxA=-INFINITY, mnB=INFINITY, mxB=-INFINITY;
    for (int t = lane; t < NPART; t += 64){
        const float* pn = pmn + ((size_t)(b*NPART + t))*8;
        const float* px = pmx + ((size_t)(b*NPART + t))*8;
        mnA = fminf(mnA, pn[2*wv]);   mxA = fmaxf(mxA, px[2*wv]);
        mnB = fminf(mnB, pn[2*wv+1]); mxB = fmaxf(mxB, px[2*wv+1]);
    }
    #pragma unroll
    for (int off=32; off; off>>=1){
        mnA = fminf(mnA, __shfl_down(mnA, off)); mxA = fmaxf(mxA, __shfl_down(mxA, off));
        mnB = fminf(mnB, __shfl_down(mnB, off)); mxB = fmaxf(mxB, __shfl_down(mxB, off));
    }
    mnA = __shfl(mnA, 0); mxA = __shfl(mxA, 0);
    mnB = __shfl(mnB, 0); mxB = __shfl(mxB, 0);
    float lo = cl[0], hi = chp[0];
    float mn0 = fminf(fmaxf(mnA, lo), hi), mx0 = fminf(fmaxf(mxA, lo), hi);
    float mn1 = fminf(fmaxf(mnB, lo), hi), mx1 = fminf(fmaxf(mxB, lo), hi);
    float cd0 = (mx0-mn0)*0.125f;
    float cd1 = (mx1-mn1)*0.125f;
    float m0[9], m1[9];
    #pragma unroll
    for (int i=0;i<9;i++){
        m0[i] = __fadd_rn(__fmul_rn((float)i, cd0), mn0);   // match ref: mul then add, no fma
        m1[i] = __fadd_rn(__fmul_rn((float)i, cd1), mn1);
    }
    int g = b*4 + wv;
    int dh, dw; group_off(wv, dh, dw);
    float* lhg = lh + wv*2048 + (lane & 31);
    __syncthreads();

    int npx = nr*257;
    for (int p = lane; p < npx; p += 64){
        int lrr = p/257;
        int w = p - lrr*257;
        float cc = band[lrr+1][w+4];
        float v0 = fminf(fmaxf(cc - band[lrr+1+dh][w+4+dw], lo), hi);
        float v1 = fminf(fmaxf(cc - band[lrr+1-dh][w+4-dw], lo), hi);
        unsigned b0=0, b1=0;
        #pragma unroll
        for (int i=0;i<8;i++){
            b0 |= (v0>=m0[i] && v0<=m0[i+1]) ? (1u<<i) : 0u;  // boundary values hit 2 bins, like ref
            b1 |= (v1>=m1[i] && v1<=m1[i+1]) ? (1u<<i) : 0u;
        }
        float pr = v0*v1;
        unsigned bb0=b0;
        while (bb0){
            int i = __ffs(bb0)-1; bb0 &= bb0-1;
            unsigned bb1=b1;
            while (bb1){
                int j = __ffs(bb1)-1; bb1 &= bb1-1;
                atomicAdd(&lhg[(i*8+j)*32], pr);
            }
        }
    }
    __syncthreads();
    float acc = 0.f;
    #pragma unroll
    for (int r=0;r<32;r++) acc += lh[(wv*64 + lane)*32 + ((lane + r)&31)];
    if (acc != 0.f) atomicAdd(&hist[g*64 + lane], acc);
}

// ---- KPRE: per-batch stats. grid (BATCH). ----
// stats[b*NSTAT]: [0..7]=glvl, [8..15]=gstat(mean0,rstd0,...), [16..271]=hh[4][64]
__global__ __launch_bounds__(256) void kpre(const float* __restrict__ hist,
                    const float* __restrict__ pmn, const float* __restrict__ pmx,
                    const float* __restrict__ cl, const float* __restrict__ chp,
                    const float* __restrict__ we, const float* __restrict__ be,
                    float* __restrict__ stats){
    __shared__ float wred[4][16];
    __shared__ float gmn[8], gmx[8];
    __shared__ float gstat[8];
    __shared__ float glvl[8];
    __shared__ float sred[4];
    __shared__ float hh[4][64];
    int b = blockIdx.x;
    int tid = threadIdx.x, wv = tid >> 6, lane = tid & 63;

    // minmax reduce over NPART partial sets (R5 k3 preamble verbatim)
    float rmn[8], rmx[8];
    #pragma unroll
    for (int q=0;q<8;q++){ rmn[q]=INFINITY; rmx[q]=-INFINITY; }
    for (int t = tid; t < NPART; t += 256){
        const float* pn = pmn + ((size_t)(b*NPART + t))*8;
        const float* px = pmx + ((size_t)(b*NPART + t))*8;
        #pragma unroll
        for (int q=0;q<8;q++){ rmn[q]=fminf(rmn[q],pn[q]); rmx[q]=fmaxf(rmx[q],px[q]); }
    }
    #pragma unroll
    for (int off=32; off; off>>=1){
        #pragma unroll
        for (int q=0;q<8;q++){
            rmn[q] = fminf(rmn[q], __shfl_down(rmn[q], off));
            rmx[q] = fmaxf(rmx[q], __shfl_down(rmx[q], off));
        }
    }
    if (lane == 0){
        #pragma unroll
        for (int q=0;q<8;q++){ wred[wv][q]=rmn[q]; wred[wv][8+q]=rmx[q]; }
    }
    // hist sum partial
    float ps = 0.f;
    for (int t = tid; t < 4096; t += 256) ps += hist[t];
    #pragma unroll
    for (int off=32; off; off>>=1) ps += __shfl_down(ps, off);
    if (lane == 0) sred[wv] = ps;
    __syncthreads();

    if (tid < 8)
        gmn[tid] = fminf(fminf(wred[0][tid],wred[1][tid]), fminf(wred[2][tid],wred[3][tid]));
    else if (tid < 16){
        int q = tid-8;
        gmx[q] = fmaxf(fmaxf(wred[0][8+q],wred[1][8+q]), fmaxf(wred[2][8+q],wred[3][8+q]));
    }
    float S = sred[0]+sred[1]+sred[2]+sred[3];
    for (int t = tid; t < 256; t += 256)
        hh[t>>6][t&63] = hist[b*256 + t] / S;
    __syncthreads();

    float lo = cl[0], hi = chp[0];
    float mn0 = fminf(fmaxf(gmn[2*wv  ], lo), hi), mx0 = fminf(fmaxf(gmx[2*wv  ], lo), hi);
    float mn1 = fminf(fmaxf(gmn[2*wv+1], lo), hi), mx1 = fminf(fmaxf(gmx[2*wv+1], lo), hi);
    float lvl0 = __fadd_rn(__fmul_rn(1.0f,(mx0-mn0)*0.125f), mn0);
    float lvl1 = __fadd_rn(__fmul_rn(1.0f,(mx1-mn1)*0.125f), mn1);
    if (lane == 0){ glvl[2*wv] = lvl0; glvl[2*wv+1] = lvl1; }

    // weighted LN stats per group (R8-verified recompute path)
    const float* hhg = hh[wv];
    float pm = 0.f;
    for (int e = lane; e < 3584; e += 64){
        int ij = e/56, o = e - ij*56;
        float a = expand_a(ij, o, lvl0, lvl1, hhg, we, be);
        int lo_ = (32*o+6)/7, hi_ = (32*o+31)/7;
        pm += a * (float)(4*(hi_-lo_+1));
    }
    #pragma unroll
    for (int off=32; off; off>>=1) pm += __shfl_down(pm, off);
    pm = __shfl(pm, 0);
    float mean = pm * (1.0f/65536.0f);
    float pv = 0.f;
    for (int e = lane; e < 3584; e += 64){
        int ij = e/56, o = e - ij*56;
        float a = expand_a(ij, o, lvl0, lvl1, hhg, we, be);
        int lo_ = (32*o+6)/7, hi_ = (32*o+31)/7;
        float d = a - mean;
        pv += d*d * (float)(4*(hi_-lo_+1));
    }
    #pragma unroll
    for (int off=32; off; off>>=1) pv += __shfl_down(pv, off);
    pv = __shfl(pv, 0);
    if (lane == 0){
        gstat[wv*2+0] = mean;
        gstat[wv*2+1] = 1.0f / sqrtf(pv * (1.0f/65536.0f) + 1e-5f);
    }
    __syncthreads();

    // emit stats record — FULL 272 floats (R9 bug: tail was truncated at tid<256)
    float* st = stats + (size_t)b*NSTAT;
    for (int t = tid; t < NSTAT; t += 256){
        float v;
        if (t < 8)        v = glvl[t];
        else if (t < 16)  v = gstat[t-8];
        else              v = hh[(t-16)>>6][(t-16)&63];
        st[t] = v;
    }
}

// ---- KCP (fold + output): grid (32, BATCH). ----
__global__ __launch_bounds__(256) void kcp(const float* __restrict__ stats,
                    const float* __restrict__ we, const float* __restrict__ be,
                    const float* __restrict__ wc, const float* __restrict__ bc,
                    const float* __restrict__ wf, const float* __restrict__ bf,
                    float* __restrict__ out){
    __shared__ float hh[4][64];
    __shared__ float glvl[8];
    __shared__ float gstat[8];
    __shared__ float w9l[4*9*56];
    __shared__ float wfl[144];
    int ch = blockIdx.x, b = blockIdx.y;
    int tid = threadIdx.x;
    if (tid < 144) wfl[tid] = wf[tid];

    // load stats record — FULL 272 floats (R9 bug: only 80 hh entries were loaded)
    const float* st = stats + (size_t)b*NSTAT;
    for (int t = tid; t < NSTAT; t += 256){
        float v = st[t];
        if (t < 8)        glvl[t] = v;
        else if (t < 16)  gstat[t-8] = v;
        else              hh[(t-16)>>6][(t-16)&63] = v;
    }
    __syncthreads();

    // fold w9 rows [rm, rp] (output rows [8ch, 8ch+8), yy>>2 in [2ch-1, 2ch+2])
    int rm = (2*ch-1 > 0) ? (2*ch-1) : 0;
    int rp = (2*ch+2 < 63) ? (2*ch+2) : 63;
    int ne = (rp-rm+1)*56;
    for (int e = tid; e < ne; e += 256){
        int rr = e/56, sxc = e - rr*56;
        int ij = rm + rr;
        float hn[4];
        #pragma unroll
        for (int k=0;k<4;k++){
            float a = expand_a(ij, sxc, glvl[2*k], glvl[2*k+1], hh[k], we, be);
            hn[k] = (a - gstat[2*k]) * gstat[2*k+1];
        }
        float w9v[9] = {0,0,0,0,0,0,0,0,0};
        #pragma unroll
        for (int c2=0;c2<16;c2++){
            float hv = bc[c2];
            #pragma unroll
            for (int k=0;k<4;k++) hv += wc[c2*4+k]*hn[k];
            hv = leaky(hv);
            #pragma unroll
            for (int t=0;t<9;t++) w9v[t] += wfl[c2*9+t]*hv;
        }
        #pragma unroll
        for (int t=0;t<9;t++) w9l[rr*504 + t*56 + sxc] = w9v[t];
    }
    __syncthreads();

    float bf0 = bf[0];
    int x = tid;
    int sxm = ((x-1)*7) >> 5;
    int sx0 = (x*7) >> 5;
    int sxp = ((x+1)*7) >> 5;
    for (int yo=0; yo<8; ++yo){
        int y = ch*8 + yo;
        float acc = bf0;
        #pragma unroll
        for (int dy=0; dy<3; ++dy){
            int yy = y + dy - 1;
            if ((unsigned)yy >= 256u) continue;
            const float* wr = &w9l[((yy>>2) - rm)*504 + dy*3*56];
            if (x >= 1)   acc += wr[sxm];
                          acc += wr[56 + sx0];
            if (x <= 254) acc += wr[2*56 + sxp];
        }
        out[((size_t)(b*256 + y))*256 + x] = leaky(acc);
    }
}

extern "C" void kernel_launch(void* const* d_in, const int* in_sizes, int n_in,
                              void* d_out, int out_size, void* d_ws, size_t ws_size,
                              hipStream_t stream){
    const float* x  = (const float*)d_in[0];
    const float* cl = (const float*)d_in[1];
    const float* ch = (const float*)d_in[2];
    const float* we = (const float*)d_in[3];
    const float* be = (const float*)d_in[4];
    const float* wc = (const float*)d_in[5];
    const float* bc = (const float*)d_in[6];
    const float* wf = (const float*)d_in[7];
    const float* bf = (const float*)d_in[8];
    float* out = (float*)d_out;

    float* s = (float*)d_ws;
    size_t off = (size_t)BATCH*SBP;
    float* pmn   = s + off; off += (size_t)BATCH*NPART*8;
    float* pmx   = s + off; off += (size_t)BATCH*NPART*8;
    float* hist  = s + off; off += 4096;
    float* stats = s + off; off += (size_t)BATCH*NSTAT;

    k1<<<dim3(32,BATCH), 256, 0, stream>>>(x, s, pmn, pmx, hist);
    k2<<<dim3(64,BATCH), 256, 0, stream>>>(s, cl, ch, pmn, pmx, hist);
    kpre<<<BATCH, 256, 0, stream>>>(hist, pmn, pmx, cl, ch, we, be, stats);
    kcp<<<dim3(32,BATCH), 256, 0, stream>>>(stats, we, be, wc, bc, wf, bf, out);
}